// Round 1
// 406.019 us; speedup vs baseline: 1.1283x; 1.1283x over previous
//
#include <hip/hip_runtime.h>

#define NN 100000
#define NE 1600000
#define DF 32
#define KIT 5
#define MU 0.01f
#define NSLOT 256
#define NV4 (NN * DF / 4)
#define ELLW 36
#define AUXCAP 65536
#define NSLICE 8
#define SLICEN (NN / NSLICE)   // 12500 nodes/slice -> 1.8MB colell slice fits 4MB XCD L2

// ---------- one-time ELL build (edge_index is iteration-invariant) ----------

__global__ __launch_bounds__(256) void zero_kernel(int* __restrict__ p, int n) {
    int i = blockIdx.x * blockDim.x + threadIdx.x;
    if (i < n) p[i] = 0;
}

// Slice-partitioned fill: blockIdx%8 selects a contiguous 12500-node slice.
// Under round-robin block->XCD dispatch, all writers of a slice live on one
// XCD, so degc (50KB) + colell (1.8MB) slices stay L2-resident: scattered 4B
// stores become L2 hits instead of ~1.5M random 64B line misses. Each slice
// group rescans the full edge list (8x12.8MB sequential, L3-served) -- cheap
// streaming traded against random-write transactions. Slot order within a
// node differs from the 1-pass build; aggregation is order-independent.
// Slots >= ELLW still spill to the aux overflow list (a.s. empty at
// Poisson(16), but guarantees correctness).
__global__ __launch_bounds__(256) void ell_fill_kernel(const int* __restrict__ row,
                                                       const int* __restrict__ col,
                                                       int* __restrict__ degc,
                                                       int* __restrict__ colell,
                                                       int* __restrict__ auxcnt,
                                                       int2* __restrict__ aux) {
    const int slice = blockIdx.x & (NSLICE - 1);
    const int group = blockIdx.x >> 3;     // chunk id within this slice-group
    const int ngroups = gridDim.x >> 3;
    const int lo = slice * SLICEN;
    const int hi = lo + SLICEN;
    for (int e = group * 256 + (int)threadIdx.x; e < NE; e += ngroups * 256) {
        const int r = row[e];
        if (r >= lo && r < hi) {
            const int c = col[e];
            const int pos = atomicAdd(&degc[r], 1);
            if (pos < ELLW) {
                colell[r * ELLW + pos] = c;
            } else {
                const int a = atomicAdd(auxcnt, 1);
                if (a < AUXCAP) aux[a] = make_int2(r, c);
            }
        }
    }
}

// ---------- bf16 shadow helpers ----------

__device__ __forceinline__ unsigned int pack2bf(float a, float b) {
    unsigned int ua = __float_as_uint(a);
    unsigned int ub = __float_as_uint(b);
    return ((ua + 0x8000u) >> 16) | (((ub + 0x8000u) >> 16) << 16);
}

__device__ __forceinline__ void unpack8(uint4 v, float* f) {
    f[0] = __uint_as_float(v.x << 16);
    f[1] = __uint_as_float(v.x & 0xffff0000u);
    f[2] = __uint_as_float(v.y << 16);
    f[3] = __uint_as_float(v.y & 0xffff0000u);
    f[4] = __uint_as_float(v.z << 16);
    f[5] = __uint_as_float(v.z & 0xffff0000u);
    f[6] = __uint_as_float(v.w << 16);
    f[7] = __uint_as_float(v.w & 0xffff0000u);
}

__global__ __launch_bounds__(256) void tobf16_kernel(const float4* __restrict__ h,
                                                     uint2* __restrict__ hb) {
    int i = blockIdx.x * blockDim.x + threadIdx.x;
    if (i < NV4) {
        const float4 v = h[i];
        hb[i] = make_uint2(pack2bf(v.x, v.y), pack2bf(v.z, v.w));
    }
}

// ---------- per-iteration ----------

// One 32-lane group per NODE PAIR (R10-proven shape). lane = q(3b)*4 + f2(2b);
// a lane-quad covers one 64B bf16 row (uint4/lane). All 10 loads (2 ELL col
// vectors, 2 own rows, 8 batch gathers) issued before any consumption.
// First 32 edges per node in one batch; edges 32..deg-1 (deg<=36) in one
// guarded tail step. Invalid slots gather the node's own row (d==0 exactly).
__global__ __launch_bounds__(256) void agg_kernel(const uint4* __restrict__ hb4,
                                                  const int* __restrict__ degc,
                                                  const int* __restrict__ colell,
                                                  float* __restrict__ S,
                                                  int* __restrict__ maxslots) {
    const int lane = threadIdx.x & 31;
    const int q = lane >> 2;
    const int f2 = lane & 3;
    const int pair = (blockIdx.x * blockDim.x + threadIdx.x) >> 5;
    const int n0 = pair * 2;
    const int n1 = n0 + 1;

    const int d0 = min(degc[n0], ELLW);
    const int d1 = min(degc[n1], ELLW);

    // head loads, all independent
    const int ca = (lane < d0) ? colell[n0 * ELLW + lane] : n0;
    const int cb = (lane < d1) ? colell[n1 * ELLW + lane] : n1;
    const uint4 hru0 = hb4[n0 * 4 + f2];
    const uint4 hru1 = hb4[n1 * 4 + f2];

    uint4 u0[4], u1[4];
    #pragma unroll
    for (int j = 0; j < 4; ++j) u0[j] = hb4[__shfl(ca, 8 * j + q, 32) * 4 + f2];
    #pragma unroll
    for (int j = 0; j < 4; ++j) u1[j] = hb4[__shfl(cb, 8 * j + q, 32) * 4 + f2];

    float hr0[8], hr1[8];
    unpack8(hru0, hr0);
    unpack8(hru1, hr1);

    float acc0[8], acc1[8];
    #pragma unroll
    for (int i = 0; i < 8; ++i) { acc0[i] = 0.0f; acc1[i] = 0.0f; }
    float nmax = 0.0f;

    #pragma unroll
    for (int j = 0; j < 4; ++j) {
        float d[8];
        unpack8(u0[j], d);
        float s = 0.0f;
        #pragma unroll
        for (int i = 0; i < 8; ++i) {
            d[i] = hr0[i] - d[i];
            s = fmaf(d[i], d[i], s);
        }
        s += __shfl_xor(s, 1, 32);
        s += __shfl_xor(s, 2, 32);
        const float n = fmaxf(sqrtf(s), 1e-6f);
        nmax = fmaxf(nmax, n);
        const float w = rsqrtf(n);
        #pragma unroll
        for (int i = 0; i < 8; ++i) acc0[i] = fmaf(-d[i], w, acc0[i]);
    }
    #pragma unroll
    for (int j = 0; j < 4; ++j) {
        float d[8];
        unpack8(u1[j], d);
        float s = 0.0f;
        #pragma unroll
        for (int i = 0; i < 8; ++i) {
            d[i] = hr1[i] - d[i];
            s = fmaf(d[i], d[i], s);
        }
        s += __shfl_xor(s, 1, 32);
        s += __shfl_xor(s, 2, 32);
        const float n = fmaxf(sqrtf(s), 1e-6f);
        nmax = fmaxf(nmax, n);
        const float w = rsqrtf(n);
        #pragma unroll
        for (int i = 0; i < 8; ++i) acc1[i] = fmaf(-d[i], w, acc1[i]);
    }

    // tails: edges 32..d-1 (at most one 8-edge step since ELLW=36)
    for (int k = 32; k < d0; k += 8) {
        const int ei = k + q;
        const int c = (ei < d0) ? colell[n0 * ELLW + ei] : n0;
        const uint4 uu = hb4[c * 4 + f2];
        float d[8];
        unpack8(uu, d);
        float s = 0.0f;
        #pragma unroll
        for (int i = 0; i < 8; ++i) {
            d[i] = hr0[i] - d[i];
            s = fmaf(d[i], d[i], s);
        }
        s += __shfl_xor(s, 1, 32);
        s += __shfl_xor(s, 2, 32);
        const float n = fmaxf(sqrtf(s), 1e-6f);
        nmax = fmaxf(nmax, n);
        const float w = rsqrtf(n);
        #pragma unroll
        for (int i = 0; i < 8; ++i) acc0[i] = fmaf(-d[i], w, acc0[i]);
    }
    for (int k = 32; k < d1; k += 8) {
        const int ei = k + q;
        const int c = (ei < d1) ? colell[n1 * ELLW + ei] : n1;
        const uint4 uu = hb4[c * 4 + f2];
        float d[8];
        unpack8(uu, d);
        float s = 0.0f;
        #pragma unroll
        for (int i = 0; i < 8; ++i) {
            d[i] = hr1[i] - d[i];
            s = fmaf(d[i], d[i], s);
        }
        s += __shfl_xor(s, 1, 32);
        s += __shfl_xor(s, 2, 32);
        const float n = fmaxf(sqrtf(s), 1e-6f);
        nmax = fmaxf(nmax, n);
        const float w = rsqrtf(n);
        #pragma unroll
        for (int i = 0; i < 8; ++i) acc1[i] = fmaf(-d[i], w, acc1[i]);
    }

    // cross-quad reduce (quads hold different edges, same feats)
    #pragma unroll
    for (int m = 4; m < 32; m <<= 1) {
        #pragma unroll
        for (int i = 0; i < 8; ++i) {
            acc0[i] += __shfl_xor(acc0[i], m, 32);
            acc1[i] += __shfl_xor(acc1[i], m, 32);
        }
    }
    if (q == 0) {
        ((float4*)S)[n0 * 8 + f2 * 2] = make_float4(acc0[0], acc0[1], acc0[2], acc0[3]);
        ((float4*)S)[n0 * 8 + f2 * 2 + 1] = make_float4(acc0[4], acc0[5], acc0[6], acc0[7]);
        ((float4*)S)[n1 * 8 + f2 * 2] = make_float4(acc1[0], acc1[1], acc1[2], acc1[3]);
        ((float4*)S)[n1 * 8 + f2 * 2 + 1] = make_float4(acc1[4], acc1[5], acc1[6], acc1[7]);
    }

    nmax = fmaxf(nmax, __shfl_xor(nmax, 4, 32));
    nmax = fmaxf(nmax, __shfl_xor(nmax, 8, 32));
    nmax = fmaxf(nmax, __shfl_xor(nmax, 16, 32));
    nmax = fmaxf(nmax, __shfl_xor(nmax, 32, 64));
    if ((threadIdx.x & 63) == 0) {
        // positive floats order like ints; 0xAA poison is negative -> loses
        atomicMax(&maxslots[blockIdx.x & (NSLOT - 1)], __float_as_int(nmax));
    }
}

// overflow edges (deg > ELLW): full per-edge norm + atomic accumulate into S.
// Almost surely empty; grid-stride guarantees coverage. Runs AFTER agg (its
// plain S stores) and BEFORE update.
__global__ __launch_bounds__(256) void aux_kernel(const uint2* __restrict__ hb,
                                                  const int2* __restrict__ aux,
                                                  const int* __restrict__ auxcnt,
                                                  float* __restrict__ S,
                                                  int* __restrict__ maxslots) {
    const int n = min(*auxcnt, AUXCAP);
    for (int i = blockIdx.x * blockDim.x + threadIdx.x; i < n;
         i += gridDim.x * blockDim.x) {
        const int r = aux[i].x;
        const int c = aux[i].y;
        float d[32];
        float s = 0.0f;
        for (int j = 0; j < 8; ++j) {
            const uint2 ur = hb[r * 8 + j];
            const uint2 uc = hb[c * 8 + j];
            float fr[4], fc[4];
            fr[0] = __uint_as_float(ur.x << 16);
            fr[1] = __uint_as_float(ur.x & 0xffff0000u);
            fr[2] = __uint_as_float(ur.y << 16);
            fr[3] = __uint_as_float(ur.y & 0xffff0000u);
            fc[0] = __uint_as_float(uc.x << 16);
            fc[1] = __uint_as_float(uc.x & 0xffff0000u);
            fc[2] = __uint_as_float(uc.y << 16);
            fc[3] = __uint_as_float(uc.y & 0xffff0000u);
            #pragma unroll
            for (int k = 0; k < 4; ++k) {
                d[j * 4 + k] = fr[k] - fc[k];
                s = fmaf(d[j * 4 + k], d[j * 4 + k], s);
            }
        }
        const float nn = fmaxf(sqrtf(s), 1e-6f);
        atomicMax(&maxslots[i & (NSLOT - 1)], __float_as_int(nn));
        const float w = rsqrtf(nn);
        for (int f = 0; f < 32; ++f) atomicAdd(&S[r * DF + f], -d[f] * w);
    }
}

// h_out = h_in - MU*sqrt(M)*S (fp32), plus refresh of the bf16 shadow.
__global__ __launch_bounds__(256) void update_kernel(const float4* __restrict__ hcur,
                                                     float4* __restrict__ hnxt,
                                                     uint2* __restrict__ hb,
                                                     const float4* __restrict__ S,
                                                     const int* __restrict__ slots) {
    const int t = threadIdx.x;
    int v = slots[t];
    #pragma unroll
    for (int m = 32; m > 0; m >>= 1) v = max(v, __shfl_xor(v, m, 64));
    __shared__ int sm[4];
    __shared__ float sscale;
    if ((t & 63) == 0) sm[t >> 6] = v;
    __syncthreads();
    if (t == 0) {
        int bm = max(max(sm[0], sm[1]), max(sm[2], sm[3]));
        sscale = MU * sqrtf(__int_as_float(bm));
    }
    __syncthreads();
    const float scale = sscale;
    const int i = blockIdx.x * blockDim.x + t;
    if (i < NV4) {
        const float4 hv = hcur[i];
        const float4 sv = S[i];
        float4 o;
        o.x = hv.x - scale * sv.x;
        o.y = hv.y - scale * sv.y;
        o.z = hv.z - scale * sv.z;
        o.w = hv.w - scale * sv.w;
        hnxt[i] = o;
        hb[i] = make_uint2(pack2bf(o.x, o.y), pack2bf(o.z, o.w));
    }
}

extern "C" void kernel_launch(void* const* d_in, const int* in_sizes, int n_in,
                              void* d_out, int out_size, void* d_ws, size_t ws_size,
                              hipStream_t stream) {
    const float* h_in = (const float*)d_in[0];
    const int* row = (const int*)d_in[1];
    const int* col = row + NE;
    float* out = (float*)d_out;

    float* S = (float*)d_ws;                         // NN*DF f32   (12.8 MB)
    int* maxslots = (int*)(S + NN * DF);             // KIT*NSLOT
    int* degc = maxslots + KIT * NSLOT;              // NN
    int* auxcnt = degc + NN;                         // 1 (contiguous with degc)
    uintptr_t pa = (uintptr_t)(auxcnt + 1);
    pa = (pa + 7) & ~(uintptr_t)7;
    int2* aux = (int2*)pa;                           // AUXCAP      (0.5 MB)
    int* colell = (int*)(aux + AUXCAP);              // NN*ELLW     (14.4 MB)
    uintptr_t p = (uintptr_t)(colell + NN * ELLW);
    p = (p + 15) & ~(uintptr_t)15;
    uint2* hb = (uint2*)p;                           // NN*DF bf16  (6.4 MB)

    const int zb = (NN + 1 + 255) / 256;
    const int fb = NSLICE * 256;                     // 2048 blocks = 8 waves/SIMD,
                                                     // fully resident; slice=bid%8
    const int gb = (NN / 2 * 32 + 255) / 256;        // 6250
    const int ub = (NV4 + 255) / 256;                // 3125

    zero_kernel<<<zb, 256, 0, stream>>>(degc, NN + 1);   // degc + auxcnt
    ell_fill_kernel<<<fb, 256, 0, stream>>>(row, col, degc, colell, auxcnt, aux);
    tobf16_kernel<<<ub, 256, 0, stream>>>((const float4*)h_in, hb);

    for (int it = 0; it < KIT; ++it) {
        const float* cur = (it == 0) ? h_in : out;
        agg_kernel<<<gb, 256, 0, stream>>>((const uint4*)hb, degc, colell, S,
                                           maxslots + it * NSLOT);
        aux_kernel<<<32, 256, 0, stream>>>(hb, aux, auxcnt, S, maxslots + it * NSLOT);
        update_kernel<<<ub, 256, 0, stream>>>((const float4*)cur, (float4*)out, hb,
                                              (const float4*)S,
                                              maxslots + it * NSLOT);
    }
}